// Round 1
// baseline (137.839 us; speedup 1.0000x reference)
//
#include <hip/hip_runtime.h>
#include <hip/hip_bf16.h>

#define NB   16
#define NQ   2048
#define NKV  2048
#define DH   128
#define KVT  64
#define QW   16          // q rows per wave
#define NWAVE 4

typedef __attribute__((ext_vector_type(8))) short short8;
typedef __attribute__((ext_vector_type(4))) float f32x4;
typedef __attribute__((ext_vector_type(4))) unsigned short u16x4;

__device__ __forceinline__ unsigned short f2bf(float f) {
    union { float f; unsigned int u; } x; x.f = f;
    unsigned int r = (x.u + 0x7fffu + ((x.u >> 16) & 1u)) >> 16;
    return (unsigned short)r;
}

__global__ __launch_bounds__(256, 2)
void attn_fwd(const float* __restrict__ qg, const float* __restrict__ kg,
              const float* __restrict__ vg, const int* __restrict__ vlg,
              float* __restrict__ og) {
    __shared__ __align__(16) unsigned short lds_k[KVT * DH];        // 16 KB, swizzled rows
    __shared__ __align__(16) unsigned short lds_vt[DH * KVT];       // 16 KB, V^T swizzled
    __shared__ __align__(16) unsigned short lds_p[NWAVE][QW * KVT]; // 8 KB, per-wave P

    const int tid = threadIdx.x;
    const int lane = tid & 63;
    const int wv = tid >> 6;
    const int row16 = lane & 15;
    const int g = lane >> 4;

    const int bidx = blockIdx.x;
    const int b  = bidx >> 5;        // 32 q-tiles per batch
    const int qt = bidx & 31;
    const int q0 = qt * (QW * NWAVE) + wv * QW;

    const int vl = vlg[b];

    // Q fragments, scale folded: (1/sqrt(128)) * log2(e)
    const float QS = 1.4426950408889634f * 0.08838834764831845f;
    short8 qf[4];
    {
        const float* qp = qg + ((size_t)b * NQ + q0 + row16) * DH + g * 8;
        #pragma unroll
        for (int c = 0; c < 4; ++c) {
            f32x4 a  = *(const f32x4*)(qp + c * 32);
            f32x4 bb = *(const f32x4*)(qp + c * 32 + 4);
            union { short8 v; unsigned short u[8]; } t;
            #pragma unroll
            for (int j = 0; j < 4; ++j) {
                t.u[j]     = f2bf(a[j] * QS);
                t.u[4 + j] = f2bf(bb[j] * QS);
            }
            qf[c] = t.v;
        }
    }

    // tiles fully beyond valid_len contribute exp(-1e6-m)==0 exactly -> skip.
    // vl==0: all positions masked -> must process all tiles (uniform softmax).
    const int ntiles = (vl == 0) ? (NKV / KVT) : ((vl + KVT - 1) / KVT);

    float m2[4], ell[4];
    f32x4 oacc[8];
    #pragma unroll
    for (int r = 0; r < 4; ++r) { m2[r] = -__builtin_inff(); ell[r] = 0.f; }
    #pragma unroll
    for (int n = 0; n < 8; ++n) oacc[n] = (f32x4){0.f, 0.f, 0.f, 0.f};

    const float* kb0 = kg + (size_t)b * NKV * DH;
    const float* vb0 = vg + (size_t)b * NKV * DH;

    for (int tt = 0; tt < ntiles; ++tt) {
        __syncthreads();
        // ---- stage K tile: coalesced fp32 loads -> bf16 swizzled LDS ----
        {
            const float* kb = kb0 + (size_t)tt * KVT * DH;
            #pragma unroll
            for (int i = 0; i < 8; ++i) {
                int idx = i * 256 + tid;
                int kvr = idx >> 5;       // 0..63
                int d4  = idx & 31;       // float4 column
                f32x4 kk = *(const f32x4*)(kb + kvr * DH + d4 * 4);
                u16x4 w;
                w[0] = f2bf(kk[0]); w[1] = f2bf(kk[1]);
                w[2] = f2bf(kk[2]); w[3] = f2bf(kk[3]);
                int byte = kvr * 256 + ((d4 * 8) ^ ((kvr & 7) << 4));
                *(u16x4*)((char*)lds_k + byte) = w;
            }
        }
        // ---- stage V tile transposed: lane<->kv mapping, conflict-free scatter ----
        {
            const float* vb = vb0 + ((size_t)tt * KVT + lane) * DH;
            #pragma unroll
            for (int i = 0; i < 8; ++i) {
                int d4 = wv + i * 4;      // 0..31
                f32x4 vv = *(const f32x4*)(vb + d4 * 4);
                #pragma unroll
                for (int j = 0; j < 4; ++j) {
                    int dd = d4 * 4 + j;
                    int byte = dd * 128 + ((lane * 2) ^ ((dd & 7) << 4));
                    *(unsigned short*)((char*)lds_vt + byte) = f2bf(vv[j]);
                }
            }
        }
        __syncthreads();

        // ---- QK^T : S[q=4g+r][kv = n*16 + row16] ----
        f32x4 s[4];
        #pragma unroll
        for (int n = 0; n < 4; ++n) {
            s[n] = (f32x4){0.f, 0.f, 0.f, 0.f};
            #pragma unroll
            for (int c = 0; c < 4; ++c) {
                int krow = n * 16 + row16;
                int byte = krow * 256 + ((c * 64 + g * 16) ^ ((krow & 7) << 4));
                short8 kf = *(const short8*)((const char*)lds_k + byte);
                s[n] = __builtin_amdgcn_mfma_f32_16x16x32_bf16(qf[c], kf, s[n], 0, 0, 0);
            }
        }

        // ---- mask + online softmax (base-2 domain) ----
        const float MASKV = -1442695.0f;   // -1e6 * log2(e)
        int kvb = tt * KVT;
        #pragma unroll
        for (int n = 0; n < 4; ++n) {
            bool valid = (kvb + n * 16 + row16) < vl;
            if (!valid) {
                #pragma unroll
                for (int r = 0; r < 4; ++r) s[n][r] = MASKV;
            }
        }
        float corr[4];
        #pragma unroll
        for (int r = 0; r < 4; ++r) {
            float tm = fmaxf(fmaxf(s[0][r], s[1][r]), fmaxf(s[2][r], s[3][r]));
            #pragma unroll
            for (int off = 1; off < 16; off <<= 1)
                tm = fmaxf(tm, __shfl_xor(tm, off));
            float mn = fmaxf(m2[r], tm);
            corr[r] = __builtin_amdgcn_exp2f(m2[r] - mn);
            m2[r] = mn;
        }
        #pragma unroll
        for (int r = 0; r < 4; ++r) {
            float ps = 0.f;
            #pragma unroll
            for (int n = 0; n < 4; ++n) {
                float p = __builtin_amdgcn_exp2f(s[n][r] - m2[r]);
                s[n][r] = p;
                ps += p;
            }
            #pragma unroll
            for (int off = 1; off < 16; off <<= 1)
                ps += __shfl_xor(ps, off);
            ell[r] = ell[r] * corr[r] + ps;
        }
        #pragma unroll
        for (int n2 = 0; n2 < 8; ++n2) {
            #pragma unroll
            for (int r = 0; r < 4; ++r) oacc[n2][r] *= corr[r];
        }

        // ---- P -> per-wave LDS (bf16, A-fragment-readable, swizzled) ----
        #pragma unroll
        for (int n = 0; n < 4; ++n) {
            #pragma unroll
            for (int r = 0; r < 4; ++r) {
                int qr = g * 4 + r;
                int col = n * 16 + row16;
                int byte = qr * 128 + ((col * 2) ^ ((qr & 7) << 4));
                *(unsigned short*)((char*)lds_p[wv] + byte) = f2bf(s[n][r]);
            }
        }
        asm volatile("s_waitcnt lgkmcnt(0)" ::: "memory");

        // ---- PV : O[q][d] += P * V ----
        #pragma unroll
        for (int kc = 0; kc < 2; ++kc) {
            int pbyte = row16 * 128 + ((kc * 64 + g * 16) ^ ((row16 & 7) << 4));
            short8 pf = *(const short8*)((const char*)lds_p[wv] + pbyte);
            #pragma unroll
            for (int n2 = 0; n2 < 8; ++n2) {
                int vrow = n2 * 16 + row16;
                int vbyte = vrow * 128 + ((kc * 64 + g * 16) ^ ((vrow & 7) << 4));
                short8 vf = *(const short8*)((const char*)lds_vt + vbyte);
                oacc[n2] = __builtin_amdgcn_mfma_f32_16x16x32_bf16(pf, vf, oacc[n2], 0, 0, 0);
            }
        }
    }

    // ---- epilogue: O / ell, fp32 out ----
    float* ob = og + ((size_t)b * NQ + q0) * DH;
    float rl[4];
    #pragma unroll
    for (int r = 0; r < 4; ++r) rl[r] = 1.0f / ell[r];
    #pragma unroll
    for (int n2 = 0; n2 < 8; ++n2) {
        #pragma unroll
        for (int r = 0; r < 4; ++r)
            ob[(size_t)(g * 4 + r) * DH + n2 * 16 + row16] = oacc[n2][r] * rl[r];
    }
}

extern "C" void kernel_launch(void* const* d_in, const int* in_sizes, int n_in,
                              void* d_out, int out_size, void* d_ws, size_t ws_size,
                              hipStream_t stream) {
    const float* q  = (const float*)d_in[0];
    const float* k  = (const float*)d_in[1];
    const float* v  = (const float*)d_in[2];
    const int*   vl = (const int*)d_in[3];
    float* o = (float*)d_out;

    dim3 grid(NB * (NQ / (QW * NWAVE)));   // 16 * 32 = 512 blocks
    dim3 block(256);
    attn_fwd<<<grid, block, 0, stream>>>(q, k, v, vl, o);
}

// Round 2
// 72.593 us; speedup vs baseline: 1.8988x; 1.8988x over previous
//
#include <hip/hip_runtime.h>
#include <hip/hip_bf16.h>

#define NB    16
#define NQ    2048
#define NKV   2048
#define DH    128
#define KVT   64
#define NTILE 32          // NKV / KVT
#define QW    16          // q rows per wave
#define NWAVE 4
#define TILE_BYTES 16384  // 64*128*2
#define TILE_ELT   8192

typedef __attribute__((ext_vector_type(8))) short short8;
typedef __attribute__((ext_vector_type(4))) float f32x4;
typedef __attribute__((ext_vector_type(4))) unsigned short u16x4;

__device__ __forceinline__ unsigned short f2bf(float f) {
    union { float f; unsigned int u; } x; x.f = f;
    unsigned int r = (x.u + 0x7fffu + ((x.u >> 16) & 1u)) >> 16;
    return (unsigned short)r;
}

__device__ __forceinline__ void load_lds16(const void* g, void* l) {
    __builtin_amdgcn_global_load_lds(
        (const __attribute__((address_space(1))) unsigned int*)g,
        (__attribute__((address_space(3))) unsigned int*)l, 16, 0, 0);
}

// stage one 16KB tile image: 4 waves x 4 issues x 64 lanes x 16B
__device__ __forceinline__ void stage16k(const char* gsrc, char* ldst, int wv, int lane) {
    #pragma unroll
    for (int i = 0; i < 4; ++i) {
        int off = i * 4096 + wv * 1024;
        load_lds16(gsrc + off + lane * 16, ldst + off);
    }
}

// ---------------- pre-convert K -> bf16 tiles, V -> V^T bf16 tiles -----------
__global__ __launch_bounds__(256)
void preconv(const float* __restrict__ kg, const float* __restrict__ vg,
             const int* __restrict__ vlg,
             unsigned short* __restrict__ kws, unsigned short* __restrict__ vws) {
    __shared__ __align__(16) unsigned short lv[TILE_ELT];   // 16 KB temp
    const int tid = threadIdx.x;
    const int rb = (blockIdx.x & 7) * 64 + (blockIdx.x >> 3);   // XCD chunking
    const int b = rb >> 5, t = rb & 31;
    const int vl = vlg[b];
    const int ntiles = (vl == 0) ? NTILE : ((vl + KVT - 1) >> 6);
    if (t >= ntiles) return;

    const float* kb = kg + ((size_t)b * NKV + t * KVT) * DH;
    const float* vb = vg + ((size_t)b * NKV + t * KVT) * DH;
    char* kimg = (char*)(kws + (size_t)(b * NTILE + t) * TILE_ELT);
    char* vimg = (char*)(vws + (size_t)(b * NTILE + t) * TILE_ELT);

    #pragma unroll
    for (int p = 0; p < 4; ++p) {
        int idx = p * 256 + tid;
        int row = idx >> 4, ch = idx & 15;
        // K: row-major swizzled image (same function the attn kernel reads)
        f32x4 a = *(const f32x4*)(kb + row * DH + ch * 8);
        f32x4 c = *(const f32x4*)(kb + row * DH + ch * 8 + 4);
        union { short8 v; unsigned short u[8]; } w;
        #pragma unroll
        for (int j = 0; j < 4; ++j) { w.u[j] = f2bf(a[j]); w.u[4 + j] = f2bf(c[j]); }
        *(short8*)(kimg + row * 256 + ((ch * 16) ^ ((row & 7) << 4))) = w.v;
        // V: into LDS (swizzled for conflict-free transpose read)
        f32x4 va = *(const f32x4*)(vb + row * DH + ch * 8);
        f32x4 vc = *(const f32x4*)(vb + row * DH + ch * 8 + 4);
        union { short8 v; unsigned short u[8]; } w2;
        #pragma unroll
        for (int j = 0; j < 4; ++j) { w2.u[j] = f2bf(va[j]); w2.u[4 + j] = f2bf(vc[j]); }
        *(short8*)((char*)lv + row * 256 + ((ch * 16) ^ (((row >> 3) & 7) << 4))) = w2.v;
    }
    __syncthreads();
    // transpose out: V^T rows d (128B each), coalesced 16B writes
    #pragma unroll
    for (int p = 0; p < 4; ++p) {
        int task = p * 256 + tid;
        int c = task & 7, d = task >> 3;        // c: kv chunk of 8, d: 0..127
        union { short8 v; unsigned short u[8]; } w;
        #pragma unroll
        for (int j = 0; j < 8; ++j) {
            int kv = c * 8 + j;
            w.u[j] = *(const unsigned short*)((const char*)lv + kv * 256 + ((d * 2) ^ (((kv >> 3) & 7) << 4)));
        }
        *(short8*)(vimg + d * 128 + ((c * 16) ^ ((d & 7) << 4))) = w.v;
    }
}

// ---------------- main attention kernel (bf16 tiles from d_ws) --------------
__global__ __launch_bounds__(256, 2)
void attn_fwd2(const float* __restrict__ qg,
               const unsigned short* __restrict__ kws,
               const unsigned short* __restrict__ vws,
               const int* __restrict__ vlg, float* __restrict__ og) {
    __shared__ __align__(16) unsigned short lds_k[2][TILE_ELT];   // 32 KB dbuf
    __shared__ __align__(16) unsigned short lds_v[TILE_ELT];      // 16 KB
    __shared__ __align__(16) unsigned short lds_p[NWAVE][QW * KVT]; // 8 KB

    const int tid = threadIdx.x;
    const int lane = tid & 63;
    const int wv = tid >> 6;
    const int row16 = lane & 15;
    const int g = lane >> 4;

    const int rb = (blockIdx.x & 7) * 64 + (blockIdx.x >> 3);   // XCD chunking
    const int b = rb >> 5;
    const int qt = rb & 31;
    const int q0 = qt * (QW * NWAVE) + wv * QW;
    const int vl = vlg[b];

    // Q fragments, scale folded: (1/sqrt(128)) * log2(e)
    const float QS = 1.4426950408889634f * 0.08838834764831845f;
    short8 qf[4];
    {
        const float* qp = qg + ((size_t)b * NQ + q0 + row16) * DH + g * 8;
        #pragma unroll
        for (int c = 0; c < 4; ++c) {
            f32x4 a  = *(const f32x4*)(qp + c * 32);
            f32x4 bb = *(const f32x4*)(qp + c * 32 + 4);
            union { short8 v; unsigned short u[8]; } t;
            #pragma unroll
            for (int j = 0; j < 4; ++j) { t.u[j] = f2bf(a[j] * QS); t.u[4 + j] = f2bf(bb[j] * QS); }
            qf[c] = t.v;
        }
    }

    const int ntiles = (vl == 0) ? NTILE : ((vl + KVT - 1) >> 6);

    float m2[4], ell[4];
    f32x4 oacc[8];
    #pragma unroll
    for (int r = 0; r < 4; ++r) { m2[r] = -__builtin_inff(); ell[r] = 0.f; }
    #pragma unroll
    for (int n = 0; n < 8; ++n) oacc[n] = (f32x4){0.f, 0.f, 0.f, 0.f};

    const char* kbase = (const char*)kws + (size_t)b * NTILE * TILE_BYTES;
    const char* vbase = (const char*)vws + (size_t)b * NTILE * TILE_BYTES;

    // prologue: K tile 0 -> buf 0
    stage16k(kbase, (char*)lds_k, wv, lane);
    asm volatile("s_waitcnt vmcnt(0)" ::: "memory");
    __syncthreads();

    int cur = 0;
    for (int tt = 0; tt < ntiles; ++tt) {
        const bool has_next = (tt + 1 < ntiles);
        // stage V(tt) first, then prefetch K(tt+1) (order matters for vmcnt(4))
        stage16k(vbase + (size_t)tt * TILE_BYTES, (char*)lds_v, wv, lane);
        if (has_next)
            stage16k(kbase + (size_t)(tt + 1) * TILE_BYTES,
                     (char*)lds_k + (cur ^ 1) * TILE_BYTES, wv, lane);

        // ---- QK^T on lds_k[cur] ----
        const char* kbuf = (const char*)lds_k + cur * TILE_BYTES;
        f32x4 s[4];
        #pragma unroll
        for (int n = 0; n < 4; ++n) {
            s[n] = (f32x4){0.f, 0.f, 0.f, 0.f};
            int krow = n * 16 + row16;
            #pragma unroll
            for (int c = 0; c < 4; ++c) {
                short8 kf = *(const short8*)(kbuf + krow * 256 + ((c * 64 + g * 16) ^ ((krow & 7) << 4)));
                s[n] = __builtin_amdgcn_mfma_f32_16x16x32_bf16(qf[c], kf, s[n], 0, 0, 0);
            }
        }

        // ---- mask (last tile / vl==0 only) ----
        const float MASKV = -1442695.0f;   // -1e6 * log2(e)
        if (vl == 0 || tt == ntiles - 1) {
            int kvb = tt * KVT;
            #pragma unroll
            for (int n = 0; n < 4; ++n) {
                if (kvb + n * 16 + row16 >= vl) {
                    #pragma unroll
                    for (int r = 0; r < 4; ++r) s[n][r] = MASKV;
                }
            }
        }

        // ---- online softmax with defer-max (THR = 8 in log2 domain) ----
        float tm[4];
        bool need = false;
        #pragma unroll
        for (int r = 0; r < 4; ++r) {
            float t0 = fmaxf(fmaxf(s[0][r], s[1][r]), fmaxf(s[2][r], s[3][r]));
            #pragma unroll
            for (int off = 1; off < 16; off <<= 1) t0 = fmaxf(t0, __shfl_xor(t0, off));
            tm[r] = t0;
            need = need || (t0 > m2[r] + 8.0f);
        }
        if (__any(need)) {
            #pragma unroll
            for (int r = 0; r < 4; ++r) {
                float mn = fmaxf(m2[r], tm[r]);
                float corr = __builtin_amdgcn_exp2f(m2[r] - mn);
                m2[r] = mn; ell[r] *= corr;
                #pragma unroll
                for (int n2 = 0; n2 < 8; ++n2) oacc[n2][r] *= corr;
            }
        }
        #pragma unroll
        for (int r = 0; r < 4; ++r) {
            float ps = 0.f;
            #pragma unroll
            for (int n = 0; n < 4; ++n) {
                float p = __builtin_amdgcn_exp2f(s[n][r] - m2[r]);
                s[n][r] = p; ps += p;
            }
            #pragma unroll
            for (int off = 1; off < 16; off <<= 1) ps += __shfl_xor(ps, off);
            ell[r] += ps;
        }

        // ---- P -> per-wave LDS (bf16, swizzled) ----
        #pragma unroll
        for (int n = 0; n < 4; ++n) {
            #pragma unroll
            for (int r = 0; r < 4; ++r) {
                int qr = g * 4 + r;
                int col = n * 16 + row16;
                __hip_bfloat16 h = __float2bfloat16(s[n][r]);
                *(unsigned short*)((char*)lds_p[wv] + qr * 128 + ((col * 2) ^ ((qr & 7) << 4))) =
                    *reinterpret_cast<unsigned short*>(&h);
            }
        }
        asm volatile("s_waitcnt lgkmcnt(0)" ::: "memory");

        // V(tt) staged by all waves must be visible: own loads done + barrier
        if (has_next) asm volatile("s_waitcnt vmcnt(4)" ::: "memory");
        else          asm volatile("s_waitcnt vmcnt(0)" ::: "memory");
        __syncthreads();

        // ---- PV on lds_v + lds_p ----
        #pragma unroll
        for (int kc = 0; kc < 2; ++kc) {
            short8 pf = *(const short8*)((const char*)lds_p[wv] + row16 * 128 +
                                         ((kc * 64 + g * 16) ^ ((row16 & 7) << 4)));
            #pragma unroll
            for (int n2 = 0; n2 < 8; ++n2) {
                int vrow = n2 * 16 + row16;
                short8 vf = *(const short8*)((const char*)lds_v + vrow * 128 +
                                             ((kc * 64 + g * 16) ^ ((vrow & 7) << 4)));
                oacc[n2] = __builtin_amdgcn_mfma_f32_16x16x32_bf16(pf, vf, oacc[n2], 0, 0, 0);
            }
        }

        if (has_next) {
            asm volatile("s_waitcnt vmcnt(0)" ::: "memory");  // K(tt+1) landed
            __syncthreads();  // all waves done reading lds_v / lds_k[cur]
            cur ^= 1;
        }
    }

    // ---- epilogue ----
    float* ob = og + ((size_t)b * NQ + q0) * DH;
    float rl[4];
    #pragma unroll
    for (int r = 0; r < 4; ++r) rl[r] = 1.0f / ell[r];
    #pragma unroll
    for (int n2 = 0; n2 < 8; ++n2) {
        #pragma unroll
        for (int r = 0; r < 4; ++r)
            ob[(size_t)(g * 4 + r) * DH + n2 * 16 + row16] = oacc[n2][r] * rl[r];
    }
}

// ---------------- fallback (round-1 monolithic kernel) ----------------------
__global__ __launch_bounds__(256, 2)
void attn_fwd1(const float* __restrict__ qg, const float* __restrict__ kg,
               const float* __restrict__ vg, const int* __restrict__ vlg,
               float* __restrict__ og) {
    __shared__ __align__(16) unsigned short lds_k[KVT * DH];
    __shared__ __align__(16) unsigned short lds_vt[DH * KVT];
    __shared__ __align__(16) unsigned short lds_p[NWAVE][QW * KVT];

    const int tid = threadIdx.x;
    const int lane = tid & 63;
    const int wv = tid >> 6;
    const int row16 = lane & 15;
    const int g = lane >> 4;
    const int bidx = blockIdx.x;
    const int b  = bidx >> 5;
    const int qt = bidx & 31;
    const int q0 = qt * (QW * NWAVE) + wv * QW;
    const int vl = vlg[b];

    const float QS = 1.4426950408889634f * 0.08838834764831845f;
    short8 qf[4];
    {
        const float* qp = qg + ((size_t)b * NQ + q0 + row16) * DH + g * 8;
        #pragma unroll
        for (int c = 0; c < 4; ++c) {
            f32x4 a  = *(const f32x4*)(qp + c * 32);
            f32x4 bb = *(const f32x4*)(qp + c * 32 + 4);
            union { short8 v; unsigned short u[8]; } t;
            #pragma unroll
            for (int j = 0; j < 4; ++j) { t.u[j] = f2bf(a[j] * QS); t.u[4 + j] = f2bf(bb[j] * QS); }
            qf[c] = t.v;
        }
    }
    const int ntiles = (vl == 0) ? (NKV / KVT) : ((vl + KVT - 1) / KVT);
    float m2[4], ell[4];
    f32x4 oacc[8];
    #pragma unroll
    for (int r = 0; r < 4; ++r) { m2[r] = -__builtin_inff(); ell[r] = 0.f; }
    #pragma unroll
    for (int n = 0; n < 8; ++n) oacc[n] = (f32x4){0.f, 0.f, 0.f, 0.f};
    const float* kb0 = kg + (size_t)b * NKV * DH;
    const float* vb0 = vg + (size_t)b * NKV * DH;

    for (int tt = 0; tt < ntiles; ++tt) {
        __syncthreads();
        {
            const float* kb = kb0 + (size_t)tt * KVT * DH;
            #pragma unroll
            for (int i = 0; i < 8; ++i) {
                int idx = i * 256 + tid;
                int kvr = idx >> 5, d4 = idx & 31;
                f32x4 kk = *(const f32x4*)(kb + kvr * DH + d4 * 4);
                u16x4 w;
                w[0] = f2bf(kk[0]); w[1] = f2bf(kk[1]); w[2] = f2bf(kk[2]); w[3] = f2bf(kk[3]);
                *(u16x4*)((char*)lds_k + kvr * 256 + ((d4 * 8) ^ ((kvr & 7) << 4))) = w;
            }
        }
        {
            const float* vb = vb0 + ((size_t)tt * KVT + lane) * DH;
            #pragma unroll
            for (int i = 0; i < 8; ++i) {
                int d4 = wv + i * 4;
                f32x4 vv = *(const f32x4*)(vb + d4 * 4);
                #pragma unroll
                for (int j = 0; j < 4; ++j) {
                    int dd = d4 * 4 + j;
                    *(unsigned short*)((char*)lds_vt + dd * 128 + ((lane * 2) ^ ((dd & 7) << 4))) = f2bf(vv[j]);
                }
            }
        }
        __syncthreads();
        f32x4 s[4];
        #pragma unroll
        for (int n = 0; n < 4; ++n) {
            s[n] = (f32x4){0.f, 0.f, 0.f, 0.f};
            #pragma unroll
            for (int c = 0; c < 4; ++c) {
                int krow = n * 16 + row16;
                short8 kf = *(const short8*)((const char*)lds_k + krow * 256 + ((c * 64 + g * 16) ^ ((krow & 7) << 4)));
                s[n] = __builtin_amdgcn_mfma_f32_16x16x32_bf16(qf[c], kf, s[n], 0, 0, 0);
            }
        }
        const float MASKV = -1442695.0f;
        int kvb = tt * KVT;
        #pragma unroll
        for (int n = 0; n < 4; ++n) {
            if (kvb + n * 16 + row16 >= vl) {
                #pragma unroll
                for (int r = 0; r < 4; ++r) s[n][r] = MASKV;
            }
        }
        float corr[4];
        #pragma unroll
        for (int r = 0; r < 4; ++r) {
            float tm = fmaxf(fmaxf(s[0][r], s[1][r]), fmaxf(s[2][r], s[3][r]));
            #pragma unroll
            for (int off = 1; off < 16; off <<= 1) tm = fmaxf(tm, __shfl_xor(tm, off));
            float mn = fmaxf(m2[r], tm);
            corr[r] = __builtin_amdgcn_exp2f(m2[r] - mn);
            m2[r] = mn;
        }
        #pragma unroll
        for (int r = 0; r < 4; ++r) {
            float ps = 0.f;
            #pragma unroll
            for (int n = 0; n < 4; ++n) {
                float p = __builtin_amdgcn_exp2f(s[n][r] - m2[r]);
                s[n][r] = p; ps += p;
            }
            #pragma unroll
            for (int off = 1; off < 16; off <<= 1) ps += __shfl_xor(ps, off);
            ell[r] = ell[r] * corr[r] + ps;
        }
        #pragma unroll
        for (int n2 = 0; n2 < 8; ++n2) {
            #pragma unroll
            for (int r = 0; r < 4; ++r) oacc[n2][r] *= corr[r];
        }
        #pragma unroll
        for (int n = 0; n < 4; ++n) {
            #pragma unroll
            for (int r = 0; r < 4; ++r) {
                int qr = g * 4 + r;
                int col = n * 16 + row16;
                *(unsigned short*)((char*)lds_p[wv] + qr * 128 + ((col * 2) ^ ((qr & 7) << 4))) = f2bf(s[n][r]);
            }
        }
        asm volatile("s_waitcnt lgkmcnt(0)" ::: "memory");
        #pragma unroll
        for (int kc = 0; kc < 2; ++kc) {
            short8 pf = *(const short8*)((const char*)lds_p[wv] + row16 * 128 + ((kc * 64 + g * 16) ^ ((row16 & 7) << 4)));
            #pragma unroll
            for (int n2 = 0; n2 < 8; ++n2) {
                int vrow = n2 * 16 + row16;
                short8 vf = *(const short8*)((const char*)lds_vt + vrow * 128 + ((kc * 64 + g * 16) ^ ((vrow & 7) << 4)));
                oacc[n2] = __builtin_amdgcn_mfma_f32_16x16x32_bf16(pf, vf, oacc[n2], 0, 0, 0);
            }
        }
    }
    float* ob = og + ((size_t)b * NQ + q0) * DH;
    float rl[4];
    #pragma unroll
    for (int r = 0; r < 4; ++r) rl[r] = 1.0f / ell[r];
    #pragma unroll
    for (int n2 = 0; n2 < 8; ++n2) {
        #pragma unroll
        for (int r = 0; r < 4; ++r)
            ob[(size_t)(g * 4 + r) * DH + n2 * 16 + row16] = oacc[n2][r] * rl[r];
    }
}

extern "C" void kernel_launch(void* const* d_in, const int* in_sizes, int n_in,
                              void* d_out, int out_size, void* d_ws, size_t ws_size,
                              hipStream_t stream) {
    const float* q  = (const float*)d_in[0];
    const float* k  = (const float*)d_in[1];
    const float* v  = (const float*)d_in[2];
    const int*   vl = (const int*)d_in[3];
    float* o = (float*)d_out;

    const size_t WS_NEED = (size_t)2 * NB * NTILE * TILE_BYTES;  // 16 MB
    if (ws_size >= WS_NEED) {
        unsigned short* kws = (unsigned short*)d_ws;
        unsigned short* vws = (unsigned short*)((char*)d_ws + (size_t)NB * NTILE * TILE_BYTES);
        preconv<<<dim3(NB * NTILE), dim3(256), 0, stream>>>(k, v, vl, kws, vws);
        attn_fwd2<<<dim3(NB * NTILE), dim3(256), 0, stream>>>(q, kws, vws, vl, o);
    } else {
        attn_fwd1<<<dim3(NB * (NQ / (QW * NWAVE))), dim3(256), 0, stream>>>(q, k, v, vl, o);
    }
}

// Round 3
// 69.900 us; speedup vs baseline: 1.9719x; 1.0385x over previous
//
#include <hip/hip_runtime.h>
#include <hip/hip_bf16.h>

#define NB    16
#define NQ    2048
#define NKV   2048
#define DH    128
#define KVT   64
#define NTILE 32          // NKV / KVT
#define TILE_BYTES 16384  // 64*128*2
#define TILE_ELT   8192

typedef __attribute__((ext_vector_type(8))) short short8;
typedef __attribute__((ext_vector_type(4))) float f32x4;

__device__ __forceinline__ unsigned short f2bf(float f) {
    union { float f; unsigned int u; } x; x.f = f;
    unsigned int r = (x.u + 0x7fffu + ((x.u >> 16) & 1u)) >> 16;
    return (unsigned short)r;
}

__device__ __forceinline__ void load_lds16(const void* g, void* l) {
    __builtin_amdgcn_global_load_lds(
        (const __attribute__((address_space(1))) unsigned int*)g,
        (__attribute__((address_space(3))) unsigned int*)l, 16, 0, 0);
}

// ---------------- pre-convert K -> bf16 tiles, V -> V^T bf16 tiles -----------
__global__ __launch_bounds__(256)
void preconv(const float* __restrict__ kg, const float* __restrict__ vg,
             const int* __restrict__ vlg,
             unsigned short* __restrict__ kws, unsigned short* __restrict__ vws) {
    __shared__ __align__(16) unsigned short lv[TILE_ELT];   // 16 KB temp
    const int tid = threadIdx.x;
    const int rb = (blockIdx.x & 7) * 64 + (blockIdx.x >> 3);   // XCD chunking
    const int b = rb >> 5, t = rb & 31;
    const int vl = vlg[b];
    const int ntiles = (vl == 0) ? NTILE : ((vl + KVT - 1) >> 6);
    if (t >= ntiles) return;

    const float* kb = kg + ((size_t)b * NKV + t * KVT) * DH;
    const float* vb = vg + ((size_t)b * NKV + t * KVT) * DH;
    char* kimg = (char*)(kws + (size_t)(b * NTILE + t) * TILE_ELT);
    char* vimg = (char*)(vws + (size_t)(b * NTILE + t) * TILE_ELT);

    #pragma unroll
    for (int p = 0; p < 4; ++p) {
        int idx = p * 256 + tid;
        int row = idx >> 4, ch = idx & 15;
        f32x4 a = *(const f32x4*)(kb + row * DH + ch * 8);
        f32x4 c = *(const f32x4*)(kb + row * DH + ch * 8 + 4);
        union { short8 v; unsigned short u[8]; } w;
        #pragma unroll
        for (int j = 0; j < 4; ++j) { w.u[j] = f2bf(a[j]); w.u[4 + j] = f2bf(c[j]); }
        *(short8*)(kimg + row * 256 + ((ch * 16) ^ ((row & 7) << 4))) = w.v;
        f32x4 va = *(const f32x4*)(vb + row * DH + ch * 8);
        f32x4 vc = *(const f32x4*)(vb + row * DH + ch * 8 + 4);
        union { short8 v; unsigned short u[8]; } w2;
        #pragma unroll
        for (int j = 0; j < 4; ++j) { w2.u[j] = f2bf(va[j]); w2.u[4 + j] = f2bf(vc[j]); }
        *(short8*)((char*)lv + row * 256 + ((ch * 16) ^ (((row >> 3) & 7) << 4))) = w2.v;
    }
    __syncthreads();
    // transpose out: V^T rows d (128B each), coalesced 16B writes
    #pragma unroll
    for (int p = 0; p < 4; ++p) {
        int task = p * 256 + tid;
        int c = task & 7, d = task >> 3;
        union { short8 v; unsigned short u[8]; } w;
        #pragma unroll
        for (int j = 0; j < 8; ++j) {
            int kv = c * 8 + j;
            w.u[j] = *(const unsigned short*)((const char*)lv + kv * 256 + ((d * 2) ^ (((kv >> 3) & 7) << 4)));
        }
        *(short8*)(vimg + d * 128 + ((c * 16) ^ ((d & 7) << 4))) = w.v;
    }
}

// ---------------- main attention: no-reduce softmax, ones-MFMA ell ----------
__global__ __launch_bounds__(128, 2)
void attn_fwd3(const float* __restrict__ qg,
               const unsigned short* __restrict__ kws,
               const unsigned short* __restrict__ vws,
               const int* __restrict__ vlg, float* __restrict__ og) {
    __shared__ __align__(16) unsigned short lds_k[TILE_ELT];       // 16 KB
    __shared__ __align__(16) unsigned short lds_v[TILE_ELT];       // 16 KB
    __shared__ __align__(16) unsigned short lds_p[2][16 * KVT];    // 4 KB

    const int tid = threadIdx.x;
    const int lane = tid & 63;
    const int wv = tid >> 6;
    const int row16 = lane & 15;
    const int g = lane >> 4;

    const int bid = blockIdx.x;
    const int b  = bid & 15;          // interleave batches across CUs for balance
    const int qt = bid >> 4;          // 0..63
    const int q0 = qt * 32 + wv * 16;
    const int vl = vlg[b];

    // Q fragments, scale folded: (1/sqrt(128)) * log2(e)
    const float QS = 1.4426950408889634f * 0.08838834764831845f;
    short8 qf[4];
    {
        const float* qp = qg + ((size_t)b * NQ + q0 + row16) * DH + g * 8;
        #pragma unroll
        for (int c = 0; c < 4; ++c) {
            f32x4 a  = *(const f32x4*)(qp + c * 32);
            f32x4 bb = *(const f32x4*)(qp + c * 32 + 4);
            union { short8 v; unsigned short u[8]; } t;
            #pragma unroll
            for (int j = 0; j < 4; ++j) { t.u[j] = f2bf(a[j] * QS); t.u[4 + j] = f2bf(bb[j] * QS); }
            qf[c] = t.v;
        }
    }

    const int ntiles = (vl == 0) ? NTILE : ((vl + KVT - 1) >> 6);
    // softmax is scale-invariant: use unnormalized P = exp2(s). Masked s=-1e6*log2e
    // gives exp2 == 0 exactly. vl==0: all masked equal -> use 0 so P=1 (uniform).
    const float MASKV = (vl == 0) ? 0.0f : -1442695.0f;

    f32x4 oacc[8];
    f32x4 ellacc = (f32x4){0.f, 0.f, 0.f, 0.f};
    #pragma unroll
    for (int n = 0; n < 8; ++n) oacc[n] = (f32x4){0.f, 0.f, 0.f, 0.f};
    short8 ones;
    {
        union { short8 v; unsigned short u[8]; } t;
        #pragma unroll
        for (int j = 0; j < 8; ++j) t.u[j] = 0x3F80;  // bf16 1.0
        ones = t.v;
    }

    const char* kbase = (const char*)kws + (size_t)b * NTILE * TILE_BYTES;
    const char* vbase = (const char*)vws + (size_t)b * NTILE * TILE_BYTES;

    for (int tt = 0; tt < ntiles; ++tt) {
        __syncthreads();
        // ---- stage K and V tiles (pre-converted bf16 images, linear copy) ----
        const char* ks = kbase + (size_t)tt * TILE_BYTES;
        const char* vs = vbase + (size_t)tt * TILE_BYTES;
        #pragma unroll
        for (int i = 0; i < 8; ++i) {
            int off = i * 2048 + wv * 1024;
            load_lds16(ks + off + lane * 16, (char*)lds_k + off);
            load_lds16(vs + off + lane * 16, (char*)lds_v + off);
        }
        asm volatile("s_waitcnt vmcnt(0)" ::: "memory");
        __syncthreads();

        // ---- QK^T : s[n][r] = S[q=g*4+r][kv = n*16 + row16] ----
        f32x4 s[4];
        __builtin_amdgcn_s_setprio(1);
        #pragma unroll
        for (int n = 0; n < 4; ++n) {
            s[n] = (f32x4){0.f, 0.f, 0.f, 0.f};
            int krow = n * 16 + row16;
            #pragma unroll
            for (int c = 0; c < 4; ++c) {
                short8 kf = *(const short8*)((const char*)lds_k + krow * 256 +
                                             ((c * 64 + g * 16) ^ ((krow & 7) << 4)));
                s[n] = __builtin_amdgcn_mfma_f32_16x16x32_bf16(qf[c], kf, s[n], 0, 0, 0);
            }
        }
        __builtin_amdgcn_s_setprio(0);

        // ---- mask (last tile only; vl==0 masks everything to 0) ----
        if (vl == 0 || tt == ntiles - 1) {
            int kvb = tt * KVT;
            #pragma unroll
            for (int n = 0; n < 4; ++n) {
                if (kvb + n * 16 + row16 >= vl) {
                    #pragma unroll
                    for (int r = 0; r < 4; ++r) s[n][r] = MASKV;
                }
            }
        }

        // ---- P = exp2(s) (no max, no sum: scale-invariant), write to LDS ----
        // write swizzle swz(q) = (q>>2) ^ ((q&3)<<1): 4 q-rows per instr land on
        // 4 distinct 16B slots -> 2-way max (free); read side balanced.
        #pragma unroll
        for (int n = 0; n < 4; ++n) {
            #pragma unroll
            for (int r = 0; r < 4; ++r) {
                float p = __builtin_amdgcn_exp2f(s[n][r]);
                int qr = g * 4 + r;
                int swz = (g ^ (r << 1)) & 7;
                __hip_bfloat16 h = __float2bfloat16(p);
                *(unsigned short*)((char*)lds_p[wv] + qr * 128 +
                                   (((n * 16 + row16) * 2) ^ (swz << 4))) =
                    *reinterpret_cast<unsigned short*>(&h);
            }
        }
        asm volatile("s_waitcnt lgkmcnt(0)" ::: "memory");

        // ---- PV + ell (ones-column MFMA) ----
        const int swzr = ((row16 >> 2) ^ ((row16 & 3) << 1)) & 7;
        __builtin_amdgcn_s_setprio(1);
        #pragma unroll
        for (int kc = 0; kc < 2; ++kc) {
            short8 pf = *(const short8*)((const char*)lds_p[wv] + row16 * 128 +
                                         ((kc * 64 + g * 16) ^ (swzr << 4)));
            ellacc = __builtin_amdgcn_mfma_f32_16x16x32_bf16(pf, ones, ellacc, 0, 0, 0);
            #pragma unroll
            for (int n2 = 0; n2 < 8; ++n2) {
                int vrow = n2 * 16 + row16;
                short8 vf = *(const short8*)((const char*)lds_v + vrow * 128 +
                                             ((kc * 64 + g * 16) ^ ((vrow & 7) << 4)));
                oacc[n2] = __builtin_amdgcn_mfma_f32_16x16x32_bf16(pf, vf, oacc[n2], 0, 0, 0);
            }
        }
        __builtin_amdgcn_s_setprio(0);
    }

    // ---- epilogue: O / ell ----
    float* ob = og + ((size_t)b * NQ + q0) * DH;
    float rl[4];
    #pragma unroll
    for (int r = 0; r < 4; ++r) rl[r] = 1.0f / ellacc[r];
    #pragma unroll
    for (int n2 = 0; n2 < 8; ++n2) {
        #pragma unroll
        for (int r = 0; r < 4; ++r)
            ob[(size_t)(g * 4 + r) * DH + n2 * 16 + row16] = oacc[n2][r] * rl[r];
    }
}

extern "C" void kernel_launch(void* const* d_in, const int* in_sizes, int n_in,
                              void* d_out, int out_size, void* d_ws, size_t ws_size,
                              hipStream_t stream) {
    const float* q  = (const float*)d_in[0];
    const float* k  = (const float*)d_in[1];
    const float* v  = (const float*)d_in[2];
    const int*   vl = (const int*)d_in[3];
    float* o = (float*)d_out;

    unsigned short* kws = (unsigned short*)d_ws;
    unsigned short* vws = (unsigned short*)((char*)d_ws + (size_t)NB * NTILE * TILE_BYTES);
    preconv<<<dim3(NB * NTILE), dim3(256), 0, stream>>>(k, v, vl, kws, vws);
    attn_fwd3<<<dim3(NB * 64), dim3(128), 0, stream>>>(q, kws, vws, vl, o);
}